// Round 1
// baseline (483.564 us; speedup 1.0000x reference)
//
#include <hip/hip_runtime.h>
#include <hip/hip_bf16.h>
#include <hip/hip_fp16.h>

// GCN: 3x gcn_conv + mean-pool + linear, bf16 MFMA pipeline.
// out[i] = dinv[i] * (sum_{e: dst=i} g[src_e] + g[i]) + b,  g = dinv .* (x @ W)
// G (gather source) is stored fp8 e4m3fn: halves gather traffic; errors are
// averaged over ~17 neighbors/layer and ~781 nodes at the pool -> absmax stays small.

typedef __attribute__((ext_vector_type(8))) short short8_t;
typedef __attribute__((ext_vector_type(4))) float float4_t;

__device__ __forceinline__ unsigned short f2bf(float f) {
    unsigned int u = __float_as_uint(f);
    u += 0x7FFFu + ((u >> 16) & 1u);   // round-to-nearest-even
    return (unsigned short)(u >> 16);
}
__device__ __forceinline__ float bf2f(unsigned short h) {
    return __uint_as_float(((unsigned int)h) << 16);
}

// ---- fp8 e4m3fn encode (epilogue-only; RNE via f16 bit trick) ----
// store b such that value = f16bits((b&0x7f)<<7) * 2^8  (== standard e4m3fn)
__device__ __forceinline__ unsigned char f2fp8(float v) {
    unsigned short h = __half_as_ushort(__float2half(v * 0.00390625f));  // v*2^-8, RNE
    unsigned int mag = h & 0x7fffu;
    unsigned int r = (mag + 0x3Fu + ((h >> 7) & 1u)) >> 7;               // RNE to 3-bit mantissa
    if (r > 0x7eu) r = 0x7eu;                                            // sat to 448 (no NaN)
    return (unsigned char)(((h >> 8) & 0x80u) | r);
}

// ---- fp8 decode in the gather hot loop ----
#if __has_builtin(__builtin_amdgcn_cvt_pk_f32_fp8)
typedef __attribute__((ext_vector_type(2))) float float2_t;
#define DEC_SCALE 1.0f
__device__ __forceinline__ void f8x4_acc(unsigned int dw, float* a) {
    float2_t lo = __builtin_amdgcn_cvt_pk_f32_fp8((int)dw, false);
    float2_t hi = __builtin_amdgcn_cvt_pk_f32_fp8((int)dw, true);
    a[0] += lo[0]; a[1] += lo[1]; a[2] += hi[0]; a[3] += hi[1];
}
#else
#define DEC_SCALE 256.0f  // folded into dinv at the end (all terms scale equally)
__device__ __forceinline__ void f8x4_acc(unsigned int dw, float* a) {
    #pragma unroll
    for (int b = 0; b < 4; ++b) {
        unsigned int x = (dw >> (8 * b)) & 0xffu;
        unsigned short hb = (unsigned short)(((x & 0x80u) << 8) | ((x & 0x7fu) << 7));
        a[b] += __half2float(__ushort_as_half(hb));
    }
}
#endif
__device__ __forceinline__ void f8x16_acc(uint4 v, float* a) {
    f8x4_acc(v.x, a); f8x4_acc(v.y, a + 4); f8x4_acc(v.z, a + 8); f8x4_acc(v.w, a + 12);
}

// async global->LDS, 16B per lane; LDS dest is wave-uniform base + lane*16 (m104/m108)
#define GLDS16(gp, lp)                                                          \
    __builtin_amdgcn_global_load_lds(                                           \
        (const __attribute__((address_space(1))) void*)(gp),                    \
        (__attribute__((address_space(3))) void*)(lp), 16, 0, 0)

// ---------------- prep: conv_x + conv_weights + zero(indeg/sums/cnt), one launch ----------------

__global__ __launch_bounds__(256) void prep(const float* __restrict__ x,
                                            ushort* __restrict__ Xb,
                                            const float* __restrict__ W1, ushort* __restrict__ Wt1,
                                            const float* __restrict__ W2, ushort* __restrict__ Wt2,
                                            const float* __restrict__ W3, ushort* __restrict__ Wt3,
                                            int* __restrict__ zbase,
                                            int M, int Mpad, int nzero, int nxblk) {
    int bx = blockIdx.x;
    if (bx < nxblk) {                        // conv_x: fp32 x -> bf16 Xb (padded)
        int t = bx * 256 + threadIdx.x;      // one float4 -> ushort4
        int row = t >> 7;
        ushort4 o;
        if (row < M) {
            float4 v = ((const float4*)x)[t];
            o.x = f2bf(v.x); o.y = f2bf(v.y); o.z = f2bf(v.z); o.w = f2bf(v.w);
        } else {
            o.x = o.y = o.z = o.w = 0;
        }
        if (row < Mpad) ((ushort4*)Xb)[t] = o;
    } else if (bx < nxblk + 704) {           // weight transpose+convert
        int t = (bx - nxblk) * 256 + threadIdx.x;
        if (t < 131072) {                    // Wt1 [256][512]
            int k = t & 511, n = t >> 9;
            Wt1[t] = f2bf(W1[(size_t)k * 256 + n]);
        } else if (t < 163840) {             // Wt2 [128][256]
            int u = t - 131072;
            int k = u & 255, n = u >> 8;
            Wt2[u] = f2bf(W2[(size_t)k * 128 + n]);
        } else if (t < 180224) {             // Wt3 [128][128], N=64 (rows 64.. zero)
            int u = t - 163840;
            int k = u & 127, n = u >> 7;
            Wt3[u] = (n < 64) ? f2bf(W3[(size_t)k * 64 + n]) : (ushort)0;
        }
    } else {                                 // zero indeg + sums + cnt
        int t = (bx - nxblk - 704) * 256 + threadIdx.x;
        if (t < nzero) zbase[t] = 0;
    }
}

// ---------------- CSR build ----------------

__global__ void count_indeg(const int* __restrict__ dst, int* __restrict__ indeg, int E) {
    int e = blockIdx.x * blockDim.x + threadIdx.x;
    if (e < E) atomicAdd(&indeg[dst[e]], 1);
}

__global__ __launch_bounds__(1024) void scan1(const int* __restrict__ indeg,
                                              int* __restrict__ incl,   // rowptr as temp
                                              int* __restrict__ part, int n) {
    __shared__ int sm[1024];
    int i = blockIdx.x * 1024 + threadIdx.x;
    int v = (i < n) ? indeg[i] : 0;
    sm[threadIdx.x] = v;
    __syncthreads();
    #pragma unroll
    for (int off = 1; off < 1024; off <<= 1) {
        int t = (threadIdx.x >= (unsigned)off) ? sm[threadIdx.x - off] : 0;
        __syncthreads();
        sm[threadIdx.x] += t;
        __syncthreads();
    }
    if (i < n) incl[i] = sm[threadIdx.x];
    if (threadIdx.x == 1023) part[blockIdx.x] = sm[1023];
}

__global__ __launch_bounds__(256) void scan23(const int* __restrict__ indeg,
                                              int* __restrict__ rowptr,
                                              int* __restrict__ cursor,
                                              const int* __restrict__ part,
                                              float* __restrict__ dinv,
                                              int n, int npad, int E, int nb) {
    __shared__ int ps[64];
    int tid = threadIdx.x;
    if (tid < 64) {
        int v = (tid < nb) ? part[tid] : 0;
        int orig = v;
        #pragma unroll
        for (int off = 1; off < 64; off <<= 1) {
            int u = __shfl_up(v, off, 64);
            if (tid >= off) v += u;
        }
        ps[tid] = v - orig;  // exclusive chunk offset
    }
    __syncthreads();
    int i = blockIdx.x * 256 + tid;
    if (i < n) {
        int excl = rowptr[i] - indeg[i] + ps[i >> 10];
        rowptr[i] = excl;
        cursor[i] = excl;
        dinv[i] = rsqrtf((float)indeg[i] + 1.0f);  // +1 self-loop
    } else if (i < npad) {
        dinv[i] = 0.f;                             // pad rows -> C rows are exact 0
    }
    if (i == 0) rowptr[n] = E;
}

__global__ void fill_csr(const int* __restrict__ src, const int* __restrict__ dst,
                         int* __restrict__ cursor, int* __restrict__ col, int E) {
    int e = blockIdx.x * blockDim.x + threadIdx.x;
    if (e < E) {
        int p = atomicAdd(&cursor[dst[e]], 1);
        col[p] = src[e];
    }
}

// ---------------- bf16 MFMA GEMM: C[m,n] = fp8( dinv[m] * sum_k A[m,k]*Bt[n,k] ) ----------------
// 128x128 tile, 256 threads = 4 waves (2x2), each wave 4x4 tiles of 16x16x32.
// Stores ALL Mpad rows (pad rows have A=0, dinv=0 -> exact fp8 zeros) so row N
// stays a valid zero-gather target for agg.

__device__ __forceinline__ void mfma_step(const ushort* __restrict__ Asb,
                                          const ushort* __restrict__ Bsb,
                                          int arow, int brow, int quad,
                                          float4_t (&acc)[4][4]) {
    short8_t aF[4], bF[4];
    #pragma unroll
    for (int i = 0; i < 4; ++i)
        aF[i] = *(const short8_t*)&Asb[(arow + i * 16) * 32 + quad * 8];
    #pragma unroll
    for (int j = 0; j < 4; ++j)
        bF[j] = *(const short8_t*)&Bsb[(brow + j * 16) * 32 + quad * 8];
    #pragma unroll
    for (int i = 0; i < 4; ++i)
        #pragma unroll
        for (int j = 0; j < 4; ++j)
            acc[i][j] = __builtin_amdgcn_mfma_f32_16x16x32_bf16(aF[i], bF[j], acc[i][j], 0, 0, 0);
}

__global__ __launch_bounds__(256) void gemm_mfma(const ushort* __restrict__ A,
                                                 const ushort* __restrict__ Bt,
                                                 const float* __restrict__ dinv,
                                                 unsigned char* __restrict__ C,
                                                 int Ncols, int K, int ldc) {
    __shared__ __align__(16) ushort As[2 * 4096];
    __shared__ __align__(16) ushort Bs[2 * 4096];
    int tid = threadIdx.x;
    int lane = tid & 63, w = tid >> 6;
    int wr = w >> 1, wc = w & 1;
    int bm = blockIdx.x * 128, bn = blockIdx.y * 128;

    float4_t acc[4][4];
    #pragma unroll
    for (int i = 0; i < 4; ++i)
        #pragma unroll
        for (int j = 0; j < 4; ++j) acc[i][j] = (float4_t)0.0f;

    int r0 = tid >> 2;
    int kb = (tid & 3) * 8;
    const ushort* ga0 = A + (size_t)(bm + r0) * K + kb;
    const ushort* ga1 = A + (size_t)(bm + r0 + 64) * K + kb;
    const ushort* gb0 = Bt + (size_t)(bn + r0) * K + kb;
    const ushort* gb1 = Bt + (size_t)(bn + r0 + 64) * K + kb;
    int w512 = w * 512;

#define ISSUE_DMA(kk, bufofs)                              \
    do {                                                   \
        GLDS16(ga0 + (kk), As + (bufofs) + w512);          \
        GLDS16(ga1 + (kk), As + (bufofs) + 2048 + w512);   \
        GLDS16(gb0 + (kk), Bs + (bufofs) + w512);          \
        GLDS16(gb1 + (kk), Bs + (bufofs) + 2048 + w512);   \
    } while (0)

    int arow = wr * 64 + (lane & 15);
    int brow = wc * 64 + (lane & 15);
    int quad = lane >> 4;

    ISSUE_DMA(0, 0);  // prologue -> buf0
    for (int k0 = 0; k0 < K; k0 += 64) {
        __syncthreads();                      // buf0 tile (k0) published
        ISSUE_DMA(k0 + 32, 4096);             // next tile -> buf1 (k0+32 < K always)
        mfma_step(As, Bs, arow, brow, quad, acc);
        __syncthreads();                      // buf1 tile (k0+32) published
        if (k0 + 64 < K) ISSUE_DMA(k0 + 64, 0);
        mfma_step(As + 4096, Bs + 4096, arow, brow, quad, acc);
    }
#undef ISSUE_DMA

    // C/D layout: col = lane&15, row = (lane>>4)*4 + reg
    int colb = bn + wc * 64 + (lane & 15);
    #pragma unroll
    for (int i = 0; i < 4; ++i) {
        int mb = bm + wr * 64 + i * 16 + quad * 4;
        #pragma unroll
        for (int r = 0; r < 4; ++r) {
            int m = mb + r;
            float s = dinv[m];
            #pragma unroll
            for (int j = 0; j < 4; ++j) {
                int n = colb + j * 16;
                if (n < Ncols) C[(size_t)m * ldc + n] = f2fp8(acc[i][j][r] * s);
            }
        }
    }
}

// ---------------- aggregation: edge-packed, fp8 in / bf16 out ----------------
// One wave per node; 16B (=16 fp8 feats) per lane; EPL edges share each load
// instruction. Pad lanes hold zrow (guaranteed-zero row) -> no masks.
// Cross-group shfl_xor folds partials.

template <int F, bool RELU>
__global__ __launch_bounds__(256) void agg_f8(const unsigned char* __restrict__ g,
                                              const int* __restrict__ rowptr,
                                              const int* __restrict__ col,
                                              const float* __restrict__ dinv,
                                              const float* __restrict__ bias,
                                              ushort* __restrict__ out,
                                              int n, int npad, int zrow) {
    constexpr int LPR = F / 16;              // lanes per row (16 fp8 bytes each)
    constexpr int EPL = 64 / LPR;            // edges per load instruction
    constexpr int LPG = 16 / EPL;            // loads per 16-edge flight group
    constexpr int EPT = 16;                  // fp8 elems per lane

    int wid = (int)((blockIdx.x * blockDim.x + threadIdx.x) >> 6);
    int lane = threadIdx.x & 63;
    if (wid >= npad) return;
    int h   = lane / LPR;                    // edge slot within a load
    int sub = lane & (LPR - 1);
    int off = sub * EPT;
    ushort* orow = out + (size_t)wid * F + off;

    if (wid >= n) {  // zero padded tail rows (zero-gather targets + next GEMM A)
        if (h == 0) {
            ((uint4*)orow)[0] = make_uint4(0, 0, 0, 0);
            ((uint4*)orow)[1] = make_uint4(0, 0, 0, 0);
        }
        return;
    }

    // self row: identical across h-slots (same addresses)
    const unsigned char* gofs = g + off;
    uint4 sv = *(const uint4*)(gofs + (size_t)wid * F);
    float self[EPT];
    #pragma unroll
    for (int t = 0; t < EPT; ++t) self[t] = 0.f;
    f8x16_acc(sv, self);

    float acc[EPT];
    #pragma unroll
    for (int t = 0; t < EPT; ++t) acc[t] = 0.f;

    int e0 = rowptr[wid];
    int deg = rowptr[wid + 1] - e0;

    for (int base = 0; base < deg; base += 64) {
        int cnt = min(64, deg - base);
        int ec = (lane < cnt) ? col[e0 + base + lane] : zrow;  // pad lanes -> zero row
        for (int j = 0; j < cnt; j += 16) {
            uint4 v[LPG];
            #pragma unroll
            for (int u = 0; u < LPG; ++u) {
                int id = __shfl(ec, j + u * EPL + h);          // <=j+15<64; pad->zrow
                v[u] = *(const uint4*)(gofs + (size_t)id * F);
            }
            #pragma unroll
            for (int u = 0; u < LPG; ++u) f8x16_acc(v[u], acc);
        }
    }

    // fold edge slots: lanes differing only in h hold the same features
    #pragma unroll
    for (int m = LPR; m < 64; m <<= 1)
        #pragma unroll
        for (int t = 0; t < EPT; ++t) acc[t] += __shfl_xor(acc[t], m, 64);

    float dis = dinv[wid] * DEC_SCALE;
    ushort res[EPT];
    #pragma unroll
    for (int t = 0; t < EPT; ++t) {
        float r = dis * (acc[t] + self[t]) + bias[off + t];
        if (RELU) r = fmaxf(r, 0.f);
        res[t] = f2bf(r);
    }
    if (h == 0) {
        uint pk[8];
        #pragma unroll
        for (int d = 0; d < 8; ++d)
            pk[d] = (uint)res[2 * d] | ((uint)res[2 * d + 1] << 16);
        ((uint4*)orow)[0] = make_uint4(pk[0], pk[1], pk[2], pk[3]);
        ((uint4*)orow)[1] = make_uint4(pk[4], pk[5], pk[6], pk[7]);
    }
}

// ---------------- pooling + final linear ----------------

__global__ __launch_bounds__(256) void pool_sorted(const ushort* __restrict__ h,
                                                   const int* __restrict__ batch,
                                                   float* __restrict__ sums,
                                                   float* __restrict__ cnt, int n) {
    int wave = (int)((blockIdx.x * blockDim.x + threadIdx.x) >> 6);
    int lane = threadIdx.x & 63;
    int start = wave * 64;
    if (start >= n) return;
    int end = min(start + 64, n);
    float acc = 0.f;
    int cur = batch[start];
    int runlen = 0;
    for (int i = start; i < end; ++i) {
        int b = batch[i];
        if (b != cur) {
            atomicAdd(&sums[cur * 64 + lane], acc);
            if (lane == 0) atomicAdd(&cnt[cur], (float)runlen);
            acc = 0.f;
            runlen = 0;
            cur = b;
        }
        acc += bf2f(h[(size_t)i * 64 + lane]);
        runlen++;
    }
    atomicAdd(&sums[cur * 64 + lane], acc);
    if (lane == 0) atomicAdd(&cnt[cur], (float)runlen);
}

__global__ void final_lin(const float* __restrict__ sums, const float* __restrict__ cnt,
                          const float* __restrict__ Wl, const float* __restrict__ bl,
                          float* __restrict__ out) {
    int t = threadIdx.x;  // 128 threads: (graph, j)
    int g = t >> 1, j = t & 1;
    float c = fmaxf(cnt[g], 1.0f);
    float a = 0.f;
    #pragma unroll
    for (int k = 0; k < 64; ++k) a += sums[g * 64 + k] * Wl[k * 2 + j];
    out[t] = a / c + bl[j];
}

// ---------------- launch ----------------

extern "C" void kernel_launch(void* const* d_in, const int* in_sizes, int n_in,
                              void* d_out, int out_size, void* d_ws, size_t ws_size,
                              hipStream_t stream) {
    const float* x   = (const float*)d_in[0];
    const int*   ei  = (const int*)d_in[1];
    const int*   bat = (const int*)d_in[2];
    const float* W1  = (const float*)d_in[3];
    const float* b1  = (const float*)d_in[4];
    const float* W2  = (const float*)d_in[5];
    const float* b2  = (const float*)d_in[6];
    const float* W3  = (const float*)d_in[7];
    const float* b3  = (const float*)d_in[8];
    const float* Wl  = (const float*)d_in[9];
    const float* bl  = (const float*)d_in[10];
    float* out = (float*)d_out;

    const int N = in_sizes[0] / 512;
    const int E = in_sizes[1] / 2;
    const int Mpad = ((N + 127) / 128) * 128;   // 50048
    const int* src = ei;
    const int* dst = ei + E;

    char* w = (char*)d_ws;
    auto alloc = [&](size_t bytes) {
        char* p = w;
        w += (bytes + 255) & ~(size_t)255;
        return p;
    };
    ushort* Xb        = (ushort*)alloc((size_t)Mpad * 512 * 2);  // bf16 x
    unsigned char* G  = (unsigned char*)alloc((size_t)Mpad * 256);  // fp8 gemm output
    ushort* H         = (ushort*)alloc((size_t)Mpad * 256 * 2);  // bf16 agg output
    ushort* Wt1  = (ushort*)alloc(256 * 512 * 2);
    ushort* Wt2  = (ushort*)alloc(128 * 256 * 2);
    ushort* Wt3  = (ushort*)alloc(128 * 128 * 2);
    float* dinv  = (float*)alloc((size_t)Mpad * 4);
    int* rowptr  = (int*)alloc((size_t)(N + 1) * 4);
    int* cursor  = (int*)alloc((size_t)N * 4);
    int* col     = (int*)alloc((size_t)(E + 16) * 4);
    int* part    = (int*)alloc(256 * 4);
    int nzero = N + 64 * 64 + 64;               // indeg + sums + cnt (ints/floats)
    int* indeg   = (int*)alloc((size_t)nzero * 4);
    float* sums  = (float*)(indeg + N);
    float* cnt   = sums + 64 * 64;

    // prep: conv_x + weight converts + zeroing, one launch
    int nxblk = (Mpad * 128 + 255) / 256;       // conv_x blocks (t = float4 index)
    int nzblk = (nzero + 255) / 256;
    prep<<<nxblk + 704 + nzblk, 256, 0, stream>>>(x, Xb, W1, Wt1, W2, Wt2, W3, Wt3,
                                                  indeg, N, Mpad, nzero, nxblk);

    // CSR
    count_indeg<<<(E + 255) / 256, 256, 0, stream>>>(dst, indeg, E);
    int nb = (N + 1023) / 1024;
    scan1<<<nb, 1024, 0, stream>>>(indeg, rowptr, part, N);
    scan23<<<(Mpad + 255) / 256, 256, 0, stream>>>(indeg, rowptr, cursor, part, dinv,
                                                   N, Mpad, E, nb);
    fill_csr<<<(E + 255) / 256, 256, 0, stream>>>(src, dst, cursor, col, E);

    int npad = Mpad;
    // layer 1: 512 -> 256
    gemm_mfma<<<dim3(Mpad / 128, 2), 256, 0, stream>>>(Xb, Wt1, dinv, G, 256, 512, 256);
    agg_f8<256, true><<<npad / 4, 256, 0, stream>>>(G, rowptr, col, dinv, b1, H, N, npad, N);
    // layer 2: 256 -> 128
    gemm_mfma<<<dim3(Mpad / 128, 1), 256, 0, stream>>>(H, Wt2, dinv, G, 128, 256, 128);
    agg_f8<128, true><<<npad / 4, 256, 0, stream>>>(G, rowptr, col, dinv, b2, H, N, npad, N);
    // layer 3: 128 -> 64 (Wt3 padded to 128 rows, store guarded n<64)
    gemm_mfma<<<dim3(Mpad / 128, 1), 256, 0, stream>>>(H, Wt3, dinv, G, 64, 128, 64);
    agg_f8<64, false><<<npad / 4, 256, 0, stream>>>(G, rowptr, col, dinv, b3, H, N, npad, N);

    pool_sorted<<<(N + 255) / 256, 256, 0, stream>>>(H, bat, sums, cnt, N);
    final_lin<<<1, 128, 0, stream>>>(sums, cnt, Wl, bl, out);
}

// Round 2
// 443.535 us; speedup vs baseline: 1.0903x; 1.0903x over previous
//
#include <hip/hip_runtime.h>

// GCN: 3x gcn_conv + mean-pool + linear, bf16 MFMA pipeline, fused layers.
// out[i] = dinv[i] * (sum_{e: dst=i} g[src_e] + g[i]) + b,  g = dinv .* (x @ W)
// Structure: k0 zero -> k1 prep(conv_x+weights+count) -> scan1 -> scan23
//   -> k4 gemm1+fill_csr -> k5 agg1+gemm2 (fused, LDS A-tile) -> k6 agg2+gemm3
//   -> agg3 -> pool -> final.  H1/H2 never touch global memory.

typedef __attribute__((ext_vector_type(8))) short short8_t;
typedef __attribute__((ext_vector_type(4))) float float4_t;

__device__ __forceinline__ unsigned short f2bf(float f) {
    unsigned int u = __float_as_uint(f);
    u += 0x7FFFu + ((u >> 16) & 1u);   // round-to-nearest-even
    return (unsigned short)(u >> 16);
}
__device__ __forceinline__ float bf2f(unsigned short h) {
    return __uint_as_float(((unsigned int)h) << 16);
}

// async global->LDS, 16B per lane; LDS dest is wave-uniform base + lane*16
#define GLDS16(gp, lp)                                                          \
    __builtin_amdgcn_global_load_lds(                                           \
        (const __attribute__((address_space(1))) void*)(gp),                    \
        (__attribute__((address_space(3))) void*)(lp), 16, 0, 0)

template <int DWN> struct VecT;
template <> struct VecT<2> { using type = uint2; };
template <> struct VecT<4> { using type = uint4; };

// ---------------- k0: zero indeg + sums + cnt ----------------
__global__ void zero_k(int* __restrict__ p, int n) {
    int i = blockIdx.x * blockDim.x + threadIdx.x;
    if (i < n) p[i] = 0;
}

// ---------------- k1: conv_x + weight transpose + count_indeg ----------------
__global__ __launch_bounds__(256) void prep(const float* __restrict__ x,
                                            ushort* __restrict__ Xb,
                                            const float* __restrict__ W1, ushort* __restrict__ Wt1,
                                            const float* __restrict__ W2, ushort* __restrict__ Wt2,
                                            const float* __restrict__ W3, ushort* __restrict__ Wt3,
                                            const int* __restrict__ dst, int* __restrict__ indeg,
                                            int M, int Mpad, int E, int nxblk) {
    int bx = blockIdx.x;
    if (bx < nxblk) {                        // conv_x: fp32 x -> bf16 Xb (padded)
        int t = bx * 256 + threadIdx.x;      // one float4 -> ushort4
        int row = t >> 7;
        ushort4 o;
        if (row < M) {
            float4 v = ((const float4*)x)[t];
            o.x = f2bf(v.x); o.y = f2bf(v.y); o.z = f2bf(v.z); o.w = f2bf(v.w);
        } else {
            o.x = o.y = o.z = o.w = 0;
        }
        if (row < Mpad) ((ushort4*)Xb)[t] = o;
    } else if (bx < nxblk + 672) {           // weight transpose+convert (672*256 = 172032)
        int t = (bx - nxblk) * 256 + threadIdx.x;
        if (t < 131072) {                    // Wt1 [256][512]
            int k = t & 511, nn = t >> 9;
            Wt1[t] = f2bf(W1[(size_t)k * 256 + nn]);
        } else if (t < 163840) {             // Wt2 [128][256]
            int u = t - 131072;
            int k = u & 255, nn = u >> 8;
            Wt2[u] = f2bf(W2[(size_t)k * 128 + nn]);
        } else {                             // Wt3 [64][128]
            int u = t - 163840;              // [0, 8192)
            int k = u & 127, nn = u >> 7;    // nn < 64
            Wt3[u] = f2bf(W3[(size_t)k * 64 + nn]);
        }
    } else {                                 // count_indeg (hides under conv_x)
        int t = (bx - nxblk - 672) * 256 + threadIdx.x;
        if (t < E) atomicAdd(&indeg[dst[t]], 1);
    }
}

// ---------------- CSR scan ----------------
__global__ __launch_bounds__(1024) void scan1(const int* __restrict__ indeg,
                                              int* __restrict__ incl,   // rowptr as temp
                                              int* __restrict__ part, int n) {
    __shared__ int sm[1024];
    int i = blockIdx.x * 1024 + threadIdx.x;
    int v = (i < n) ? indeg[i] : 0;
    sm[threadIdx.x] = v;
    __syncthreads();
    #pragma unroll
    for (int off = 1; off < 1024; off <<= 1) {
        int t = (threadIdx.x >= (unsigned)off) ? sm[threadIdx.x - off] : 0;
        __syncthreads();
        sm[threadIdx.x] += t;
        __syncthreads();
    }
    if (i < n) incl[i] = sm[threadIdx.x];
    if (threadIdx.x == 1023) part[blockIdx.x] = sm[1023];
}

__global__ __launch_bounds__(256) void scan23(const int* __restrict__ indeg,
                                              int* __restrict__ rowptr,
                                              int* __restrict__ cursor,
                                              const int* __restrict__ part,
                                              float* __restrict__ dinv,
                                              int n, int npad, int E, int nb) {
    __shared__ int ps[64];
    int tid = threadIdx.x;
    if (tid < 64) {
        int v = (tid < nb) ? part[tid] : 0;
        int orig = v;
        #pragma unroll
        for (int off = 1; off < 64; off <<= 1) {
            int u = __shfl_up(v, off, 64);
            if (tid >= off) v += u;
        }
        ps[tid] = v - orig;  // exclusive chunk offset
    }
    __syncthreads();
    int i = blockIdx.x * 256 + tid;
    if (i < n) {
        int excl = rowptr[i] - indeg[i] + ps[i >> 10];
        rowptr[i] = excl;
        cursor[i] = excl;
        dinv[i] = rsqrtf((float)indeg[i] + 1.0f);  // +1 self-loop
    } else if (i < npad) {
        dinv[i] = 0.f;                             // pad rows -> C rows are exact 0
    }
    if (i == 0) rowptr[n] = E;
}

// ---------------- k4: gemm1 (K=512, N=256) + fill_csr, block-partitioned ----------------
__global__ __launch_bounds__(256) void gemm1_fill(const ushort* __restrict__ A,
                                                  const ushort* __restrict__ Bt,
                                                  const float* __restrict__ dinv,
                                                  ushort* __restrict__ C,
                                                  const int* __restrict__ src,
                                                  const int* __restrict__ dst,
                                                  int* __restrict__ cursor,
                                                  int* __restrict__ colx,
                                                  int E, int ngemm) {
    __shared__ __align__(16) ushort As[2 * 4096];
    __shared__ __align__(16) ushort Bs[2 * 4096];
    int bx = blockIdx.x;
    if (bx >= ngemm) {                      // fill_csr blocks (hide under gemm)
        int e = (bx - ngemm) * 256 + threadIdx.x;
        if (e < E) {
            int p = atomicAdd(&cursor[dst[e]], 1);
            colx[p] = src[e];
        }
        return;
    }
    constexpr int K = 512;
    int tid = threadIdx.x;
    int lane = tid & 63, w = tid >> 6;
    int wr = w >> 1, wc = w & 1;
    int bm = (bx >> 1) * 128, bn = (bx & 1) * 128;

    float4_t acc[4][4];
    #pragma unroll
    for (int i = 0; i < 4; ++i)
        #pragma unroll
        for (int j = 0; j < 4; ++j) acc[i][j] = (float4_t)0.0f;

    int r0 = tid >> 2;
    int kb = (tid & 3) * 8;
    const ushort* ga0 = A + (size_t)(bm + r0) * K + kb;
    const ushort* ga1 = A + (size_t)(bm + r0 + 64) * K + kb;
    const ushort* gb0 = Bt + (size_t)(bn + r0) * K + kb;
    const ushort* gb1 = Bt + (size_t)(bn + r0 + 64) * K + kb;
    int w512 = w * 512;

#define ISSUE_DMA(kk, bufofs)                              \
    do {                                                   \
        GLDS16(ga0 + (kk), As + (bufofs) + w512);          \
        GLDS16(ga1 + (kk), As + (bufofs) + 2048 + w512);   \
        GLDS16(gb0 + (kk), Bs + (bufofs) + w512);          \
        GLDS16(gb1 + (kk), Bs + (bufofs) + 2048 + w512);   \
    } while (0)

    int arow = wr * 64 + (lane & 15);
    int brow = wc * 64 + (lane & 15);
    int quad = lane >> 4;

    ISSUE_DMA(0, 0);  // prologue -> buf0
    for (int k0 = 0; k0 < K; k0 += 64) {
        __syncthreads();
        ISSUE_DMA(k0 + 32, 4096);
        {
            short8_t aF[4], bF[4];
            #pragma unroll
            for (int i = 0; i < 4; ++i)
                aF[i] = *(const short8_t*)&As[(arow + i * 16) * 32 + quad * 8];
            #pragma unroll
            for (int j = 0; j < 4; ++j)
                bF[j] = *(const short8_t*)&Bs[(brow + j * 16) * 32 + quad * 8];
            #pragma unroll
            for (int i = 0; i < 4; ++i)
                #pragma unroll
                for (int j = 0; j < 4; ++j)
                    acc[i][j] = __builtin_amdgcn_mfma_f32_16x16x32_bf16(aF[i], bF[j], acc[i][j], 0, 0, 0);
        }
        __syncthreads();
        if (k0 + 64 < K) ISSUE_DMA(k0 + 64, 0);
        {
            short8_t aF[4], bF[4];
            #pragma unroll
            for (int i = 0; i < 4; ++i)
                aF[i] = *(const short8_t*)&As[4096 + (arow + i * 16) * 32 + quad * 8];
            #pragma unroll
            for (int j = 0; j < 4; ++j)
                bF[j] = *(const short8_t*)&Bs[4096 + (brow + j * 16) * 32 + quad * 8];
            #pragma unroll
            for (int i = 0; i < 4; ++i)
                #pragma unroll
                for (int j = 0; j < 4; ++j)
                    acc[i][j] = __builtin_amdgcn_mfma_f32_16x16x32_bf16(aF[i], bF[j], acc[i][j], 0, 0, 0);
        }
    }
#undef ISSUE_DMA

    // C/D layout: col = lane&15, row = (lane>>4)*4 + reg
    int colb = bn + wc * 64 + (lane & 15);
    #pragma unroll
    for (int i = 0; i < 4; ++i) {
        int mb = bm + wr * 64 + i * 16 + quad * 4;
        #pragma unroll
        for (int r = 0; r < 4; ++r) {
            int m = mb + r;
            float s = dinv[m];
            #pragma unroll
            for (int j = 0; j < 4; ++j) {
                int n = colb + j * 16;
                C[(size_t)m * 256 + n] = f2bf(acc[i][j][r] * s);
            }
        }
    }
}

// ---------------- fused agg + gemm: block owns 128 rows ----------------
// Phase 1: 8 waves aggregate 16 rows each (bf16 gather from g, CSR), apply
//   dinv/bias/relu, write bf16 A-tile into LDS ([FIN/32][128][32] k-chunks).
// Phase 2: MFMA with B read directly from global (Wt L2-resident),
//   epilogue scales by dinv[m], writes bf16 C = next layer's gather source.
template <int FIN, int NOUT>
__global__ __launch_bounds__(512) void agg_gemm(const ushort* __restrict__ g,
                                                const int* __restrict__ rowptr,
                                                const int* __restrict__ col,
                                                const float* __restrict__ dinv,
                                                const float* __restrict__ bias,
                                                const ushort* __restrict__ Bt,  // [NOUT][FIN]
                                                ushort* __restrict__ C,         // [Mpad][NOUT]
                                                int n, int zrow) {
    constexpr int NCH = FIN / 32;        // k-chunks
    constexpr int EPT = FIN / 32;        // features per lane (32 lanes per row)
    constexpr int DWN = EPT / 2;         // dwords per gather load
    using vec_t = typename VecT<DWN>::type;
    __shared__ __align__(16) ushort As[NCH * 128 * 32];   // 64KB (FIN=256) / 32KB (FIN=128)

    int tid = threadIdx.x;
    int lane = tid & 63, wv = tid >> 6;  // 8 waves
    int bm = blockIdx.x * 128;
    int h = lane >> 5, sub = lane & 31;  // 2 edge slots x 32 lanes/row
    int off = sub * EPT;
    const ushort* gofs = g + off;
    int cch0 = off >> 5, kk0 = off & 31;

    // ---- phase 1: aggregate ----
    for (int q = 0; q < 16; ++q) {
        int r = wv * 16 + q;
        int m = bm + r;
        ushort* ap = As + cch0 * 4096 + r * 32 + kk0;
        if (m >= n) {                    // pad row -> exact zeros (avoid NaN in MFMA)
            if (h == 0) {
                #pragma unroll
                for (int d = 0; d < DWN; ++d) ((uint*)ap)[d] = 0;
            }
            continue;
        }
        vec_t sv = *(const vec_t*)(gofs + (size_t)m * FIN);
        float self[EPT], acc[EPT];
        #pragma unroll
        for (int d = 0; d < DWN; ++d) {
            uint dw = ((const uint*)&sv)[d];
            self[2 * d]     = __uint_as_float(dw << 16);
            self[2 * d + 1] = __uint_as_float(dw & 0xffff0000u);
        }
        #pragma unroll
        for (int t = 0; t < EPT; ++t) acc[t] = 0.f;

        int e0 = rowptr[m];
        int deg = rowptr[m + 1] - e0;
        for (int base = 0; base < deg; base += 64) {
            int cnt = min(64, deg - base);
            int ec = (lane < cnt) ? col[e0 + base + lane] : zrow;  // pad lanes -> zero row
            for (int j = 0; j < cnt; j += 16) {
                vec_t v[8];
                #pragma unroll
                for (int u = 0; u < 8; ++u) {
                    int id = __shfl(ec, j + u * 2 + h);
                    v[u] = *(const vec_t*)(gofs + (size_t)id * FIN);
                }
                #pragma unroll
                for (int u = 0; u < 8; ++u)
                    #pragma unroll
                    for (int d = 0; d < DWN; ++d) {
                        uint dw = ((const uint*)&v[u])[d];
                        acc[2 * d]     += __uint_as_float(dw << 16);
                        acc[2 * d + 1] += __uint_as_float(dw & 0xffff0000u);
                    }
            }
        }
        #pragma unroll
        for (int t = 0; t < EPT; ++t) acc[t] += __shfl_xor(acc[t], 32, 64);

        if (h == 0) {
            float di = dinv[m];
            uint pk[DWN];
            #pragma unroll
            for (int d = 0; d < DWN; ++d) {
                float r0 = fmaxf(di * (acc[2 * d]     + self[2 * d])     + bias[off + 2 * d],     0.f);
                float r1 = fmaxf(di * (acc[2 * d + 1] + self[2 * d + 1]) + bias[off + 2 * d + 1], 0.f);
                pk[d] = (uint)f2bf(r0) | ((uint)f2bf(r1) << 16);
            }
            #pragma unroll
            for (int d = 0; d < DWN; ++d) ((uint*)ap)[d] = pk[d];
        }
    }
    __syncthreads();

    // ---- phase 2: C[128 x NOUT] = dinv .* (A @ Bt^T) ----
    constexpr int WC = NOUT / 32;        // waves across N
    constexpr int WR = 8 / WC;           // waves across M
    constexpr int MI = 8 / WR;           // 16-row frags per wave
    int wr = wv / WC, wc = wv % WC;
    int quad = lane >> 4, l15 = lane & 15;
    float4_t acc2[MI][2];
    #pragma unroll
    for (int i = 0; i < MI; ++i) {
        acc2[i][0] = (float4_t)0.f;
        acc2[i][1] = (float4_t)0.f;
    }
    int arowb = wr * (MI * 16) + l15;
    const ushort* bp = Bt + (size_t)(wc * 32 + l15) * FIN + quad * 8;
    #pragma unroll
    for (int c = 0; c < NCH; ++c) {
        short8_t aF[MI], bF[2];
        #pragma unroll
        for (int i = 0; i < MI; ++i)
            aF[i] = *(const short8_t*)&As[c * 4096 + (arowb + i * 16) * 32 + quad * 8];
        #pragma unroll
        for (int j = 0; j < 2; ++j)
            bF[j] = *(const short8_t*)(bp + (size_t)(j * 16) * FIN + c * 32);
        #pragma unroll
        for (int i = 0; i < MI; ++i) {
            acc2[i][0] = __builtin_amdgcn_mfma_f32_16x16x32_bf16(aF[i], bF[0], acc2[i][0], 0, 0, 0);
            acc2[i][1] = __builtin_amdgcn_mfma_f32_16x16x32_bf16(aF[i], bF[1], acc2[i][1], 0, 0, 0);
        }
    }
    #pragma unroll
    for (int i = 0; i < MI; ++i) {
        int mb = bm + wr * (MI * 16) + i * 16 + quad * 4;
        #pragma unroll
        for (int rr = 0; rr < 4; ++rr) {
            int m = mb + rr;
            float s = dinv[m];
            #pragma unroll
            for (int j = 0; j < 2; ++j) {
                int ncol = wc * 32 + j * 16 + l15;
                C[(size_t)m * NOUT + ncol] = f2bf(acc2[i][j][rr] * s);
            }
        }
    }
}

// ---------------- standalone agg (layer 3, F=64, bf16) ----------------
template <int F, bool RELU>
__global__ __launch_bounds__(256) void agg_bf(const ushort* __restrict__ g,
                                              const int* __restrict__ rowptr,
                                              const int* __restrict__ col,
                                              const float* __restrict__ dinv,
                                              const float* __restrict__ bias,
                                              ushort* __restrict__ out,
                                              int n, int npad, int zrow) {
    constexpr int EPL  = (F == 64) ? 4 : 2;  // edges per load instruction
    constexpr int SUBW = 64 / EPL;           // lanes per edge
    constexpr int EPT  = F / SUBW;           // elements per lane
    constexpr int LPG  = 16 / EPL;           // loads per 16-edge flight group
    constexpr int DWN  = EPT / 2;            // dwords per load
    using vec_t = typename VecT<DWN>::type;

    int wid = (int)((blockIdx.x * blockDim.x + threadIdx.x) >> 6);
    int lane = threadIdx.x & 63;
    if (wid >= npad) return;
    int h   = lane / SUBW;
    int sub = lane & (SUBW - 1);
    int off = sub * EPT;
    ushort* orow = out + (size_t)wid * F + off;

    if (wid >= n) {  // zero padded tail rows
        if (h == 0) {
            #pragma unroll
            for (int d = 0; d < DWN; ++d) ((uint*)orow)[d] = 0;
        }
        return;
    }

    const ushort* gofs = g + off;
    vec_t sv = *(const vec_t*)(gofs + (size_t)wid * F);
    float self[EPT];
    #pragma unroll
    for (int d = 0; d < DWN; ++d) {
        uint dw = ((const uint*)&sv)[d];
        self[2 * d]     = __uint_as_float(dw << 16);
        self[2 * d + 1] = __uint_as_float(dw & 0xffff0000u);
    }

    float acc[EPT];
    #pragma unroll
    for (int t = 0; t < EPT; ++t) acc[t] = 0.f;

    int e0 = rowptr[wid];
    int deg = rowptr[wid + 1] - e0;

    for (int base = 0; base < deg; base += 64) {
        int cnt = min(64, deg - base);
        int ec = (lane < cnt) ? col[e0 + base + lane] : zrow;
        for (int j = 0; j < cnt; j += 16) {
            vec_t v[LPG];
            #pragma unroll
            for (int u = 0; u < LPG; ++u) {
                int id = __shfl(ec, j + u * EPL + h);
                v[u] = *(const vec_t*)(gofs + (size_t)id * F);
            }
            #pragma unroll
            for (int u = 0; u < LPG; ++u)
                #pragma unroll
                for (int d = 0; d < DWN; ++d) {
                    uint dw = ((const uint*)&v[u])[d];
                    acc[2 * d]     += __uint_as_float(dw << 16);
                    acc[2 * d + 1] += __uint_as_float(dw & 0xffff0000u);
                }
        }
    }

    #pragma unroll
    for (int t = 0; t < EPT; ++t) {
        if constexpr (EPL == 4) acc[t] += __shfl_xor(acc[t], 16, 64);
        acc[t] += __shfl_xor(acc[t], 32, 64);
    }

    float di = dinv[wid];
    ushort res[EPT];
    #pragma unroll
    for (int t = 0; t < EPT; ++t) {
        float r = di * (acc[t] + self[t]) + bias[off + t];
        if (RELU) r = fmaxf(r, 0.f);
        res[t] = f2bf(r);
    }
    if (h == 0) {
        #pragma unroll
        for (int d = 0; d < DWN; ++d)
            ((uint*)orow)[d] = (uint)res[2 * d] | ((uint)res[2 * d + 1] << 16);
    }
}

// ---------------- pooling + final linear ----------------

__global__ __launch_bounds__(256) void pool_sorted(const ushort* __restrict__ h,
                                                   const int* __restrict__ batch,
                                                   float* __restrict__ sums,
                                                   float* __restrict__ cnt, int n) {
    int wave = (int)((blockIdx.x * blockDim.x + threadIdx.x) >> 6);
    int lane = threadIdx.x & 63;
    int start = wave * 64;
    if (start >= n) return;
    int end = min(start + 64, n);
    float acc = 0.f;
    int cur = batch[start];
    int runlen = 0;
    for (int i = start; i < end; ++i) {
        int b = batch[i];
        if (b != cur) {
            atomicAdd(&sums[cur * 64 + lane], acc);
            if (lane == 0) atomicAdd(&cnt[cur], (float)runlen);
            acc = 0.f;
            runlen = 0;
            cur = b;
        }
        acc += bf2f(h[(size_t)i * 64 + lane]);
        runlen++;
    }
    atomicAdd(&sums[cur * 64 + lane], acc);
    if (lane == 0) atomicAdd(&cnt[cur], (float)runlen);
}

__global__ void final_lin(const float* __restrict__ sums, const float* __restrict__ cnt,
                          const float* __restrict__ Wl, const float* __restrict__ bl,
                          float* __restrict__ out) {
    int t = threadIdx.x;  // 128 threads: (graph, j)
    int g = t >> 1, j = t & 1;
    float c = fmaxf(cnt[g], 1.0f);
    float a = 0.f;
    #pragma unroll
    for (int k = 0; k < 64; ++k) a += sums[g * 64 + k] * Wl[k * 2 + j];
    out[t] = a / c + bl[j];
}

// ---------------- launch ----------------

extern "C" void kernel_launch(void* const* d_in, const int* in_sizes, int n_in,
                              void* d_out, int out_size, void* d_ws, size_t ws_size,
                              hipStream_t stream) {
    const float* x   = (const float*)d_in[0];
    const int*   ei  = (const int*)d_in[1];
    const int*   bat = (const int*)d_in[2];
    const float* W1  = (const float*)d_in[3];
    const float* b1  = (const float*)d_in[4];
    const float* W2  = (const float*)d_in[5];
    const float* b2  = (const float*)d_in[6];
    const float* W3  = (const float*)d_in[7];
    const float* b3  = (const float*)d_in[8];
    const float* Wl  = (const float*)d_in[9];
    const float* bl  = (const float*)d_in[10];
    float* out = (float*)d_out;

    const int N = in_sizes[0] / 512;
    const int E = in_sizes[1] / 2;
    const int Mpad = ((N + 127) / 128) * 128;   // 50048
    const int* src = ei;
    const int* dst = ei + E;

    char* w = (char*)d_ws;
    auto alloc = [&](size_t bytes) {
        char* p = w;
        w += (bytes + 255) & ~(size_t)255;
        return p;
    };
    ushort* Xb   = (ushort*)alloc((size_t)Mpad * 512 * 2);  // bf16 x
    ushort* G1   = (ushort*)alloc((size_t)Mpad * 256 * 2);  // gemm1 out / agg1 gather src
    ushort* G2   = (ushort*)alloc((size_t)Mpad * 128 * 2);  // k5 out / agg2 gather src
    ushort* G3   = (ushort*)alloc((size_t)Mpad * 64 * 2);   // k6 out / agg3 gather src
    ushort* H3   = (ushort*)alloc((size_t)Mpad * 64 * 2);   // agg3 out (pool input)
    ushort* Wt1  = (ushort*)alloc(256 * 512 * 2);
    ushort* Wt2  = (ushort*)alloc(128 * 256 * 2);
    ushort* Wt3  = (ushort*)alloc(64 * 128 * 2);
    float* dinv  = (float*)alloc((size_t)Mpad * 4);
    int* rowptr  = (int*)alloc((size_t)(N + 1) * 4);
    int* cursor  = (int*)alloc((size_t)N * 4);
    int* col     = (int*)alloc((size_t)(E + 16) * 4);
    int* part    = (int*)alloc(256 * 4);
    int nzero = N + 64 * 64 + 64;               // indeg + sums + cnt
    int* indeg   = (int*)alloc((size_t)nzero * 4);
    float* sums  = (float*)(indeg + N);
    float* cnt   = sums + 64 * 64;

    // k0: zero indeg + sums + cnt
    zero_k<<<(nzero + 255) / 256, 256, 0, stream>>>(indeg, nzero);

    // k1: conv_x + weight converts + count_indeg
    int nxblk = (Mpad * 128 + 255) / 256;       // conv_x blocks (t = float4 index)
    int ncblk = (E + 255) / 256;                // 3125
    prep<<<nxblk + 672 + ncblk, 256, 0, stream>>>(x, Xb, W1, Wt1, W2, Wt2, W3, Wt3,
                                                  dst, indeg, N, Mpad, E, nxblk);

    // CSR scan
    int nb = (N + 1023) / 1024;
    scan1<<<nb, 1024, 0, stream>>>(indeg, rowptr, part, N);
    scan23<<<(Mpad + 255) / 256, 256, 0, stream>>>(indeg, rowptr, cursor, part, dinv,
                                                   N, Mpad, E, nb);

    // k4: gemm1 (512->256) + fill_csr
    int ngemm = (Mpad / 128) * 2;               // 782
    gemm1_fill<<<ngemm + ncblk, 256, 0, stream>>>(Xb, Wt1, dinv, G1, src, dst,
                                                  cursor, col, E, ngemm);

    // k5: agg1 (relu, b1) + gemm2 (256->128) fused
    agg_gemm<256, 128><<<Mpad / 128, 512, 0, stream>>>(G1, rowptr, col, dinv, b1,
                                                       Wt2, G2, N, N);
    // k6: agg2 (relu, b2) + gemm3 (128->64) fused
    agg_gemm<128, 64><<<Mpad / 128, 512, 0, stream>>>(G2, rowptr, col, dinv, b2,
                                                      Wt3, G3, N, N);
    // agg3 (b3, no relu)
    agg_bf<64, false><<<Mpad / 4, 256, 0, stream>>>(G3, rowptr, col, dinv, b3, H3,
                                                    N, Mpad, N);

    pool_sorted<<<(N + 255) / 256, 256, 0, stream>>>(H3, bat, sums, cnt, N);
    final_lin<<<1, 128, 0, stream>>>(sums, cnt, Wl, bl, out);
}